// Round 8
// baseline (420.098 us; speedup 1.0000x reference)
//
#include <hip/hip_runtime.h>
#include <math.h>

// LSTMLightweight on MI355X (R8 = R7 + anti-remat register pinning).
//   x[B,T,1] -> linear_in(1->16)+ReLU -> LSTM0(16) -> LSTM1(16) -> fc(16->8)+ReLU -> fc(8->1)
// DPP-rotation matvec, zero inner-loop LDS. h lives one-per-lane (lane j of each
// 16-lane DPP row holds h_j); each recurrent dot = 16 rotate+FMA steps on the
// VALU pipe (row_ror:S delivers lane i <- lane (i-S)&15, so weights are
// pre-rotated as W[s] = w[row][(j-s)&15] — verified correct in R7).
// R7 lesson: allocator hit VGPR=64 by REMATERIALIZING the 96 loop-invariant
// weight loads inside the loop (no scratch spill, reloads hit L1 -> invisible
// in FETCH/WRITE, but ~300 extra ops/step -> 417us at 96% VALUBusy).
// R8: after preload, every weight/bias scalar passes through an opaque
// asm volatile("" : "+v") — not remat-able, not CSE-able -> must stay resident.
// Pressure ~125 < cap 256 (launch_bounds(64,2)) -> no spill either.

#define EPW 2
#define L2E 1.4426950408889634f

typedef float v2f __attribute__((ext_vector_type(2)));

__device__ __forceinline__ float sigm(float v) {
    return __builtin_amdgcn_rcpf(1.0f + __builtin_amdgcn_exp2f(-L2E * v));
}
__device__ __forceinline__ float tanh_(float v) {
    // tanh(v) = 1 - 2/(exp(2v)+1); saturates correctly at +-inf
    return 1.0f - 2.0f * __builtin_amdgcn_rcpf(1.0f + __builtin_amdgcn_exp2f((2.0f * L2E) * v));
}

// rotate within each 16-lane DPP row: lane i <- lane (i-S)&15  (row_ror:S)
template <int S>
__device__ __forceinline__ float rot16(float v) {
    const int iv = __float_as_int(v);
    return __int_as_float(__builtin_amdgcn_update_dpp(iv, iv, 0x120 + S, 0xF, 0xF, false));
}

#define RSTEP(S, aA, aB, h, WA, WB)              \
    do {                                         \
        const float hr_ = rot16<S>(h);           \
        aA = fmaf(hr_, WA[S], aA);               \
        aB = fmaf(hr_, WB[S], aB);               \
    } while (0)

// full 16-term rotating dot over one 16-lane ring
#define DOTROT(aA, aB, h, WA, WB)                \
    do {                                         \
        aA = fmaf(h, WA[0], aA);                 \
        aB = fmaf(h, WB[0], aB);                 \
        RSTEP(1, aA, aB, h, WA, WB);             \
        RSTEP(2, aA, aB, h, WA, WB);             \
        RSTEP(3, aA, aB, h, WA, WB);             \
        RSTEP(4, aA, aB, h, WA, WB);             \
        RSTEP(5, aA, aB, h, WA, WB);             \
        RSTEP(6, aA, aB, h, WA, WB);             \
        RSTEP(7, aA, aB, h, WA, WB);             \
        RSTEP(8, aA, aB, h, WA, WB);             \
        RSTEP(9, aA, aB, h, WA, WB);             \
        RSTEP(10, aA, aB, h, WA, WB);            \
        RSTEP(11, aA, aB, h, WA, WB);            \
        RSTEP(12, aA, aB, h, WA, WB);            \
        RSTEP(13, aA, aB, h, WA, WB);            \
        RSTEP(14, aA, aB, h, WA, WB);            \
        RSTEP(15, aA, aB, h, WA, WB);            \
    } while (0)

// Finish a layer. half0 (k2=1): aA=i-pre, aB=f-pre, owns cc.
// half1 (k2=2): aA=g-pre, aB=o-pre. actA = fmaf(k2, sigm(k2*aA)-1, 1):
//   k2=1 -> sigm(aA); k2=2 -> 2*sigm(2aA)-1 = tanh(aA).
// Returns h_j valid on ALL lanes.
__device__ __forceinline__ float finishg(float aA, float aB, float k2, int half,
                                         float& cc) {
    const float s = sigm(k2 * aA);
    const float actA = fmaf(k2, s - 1.0f, 1.0f);
    const float actB = sigm(aB);
    const float xg = __shfl_xor(actA, 16, 64);  // half0 <- tanh(g); half1 <- sigm(i)
    cc = fmaf(actB, cc, actA * xg);             // real c on half0; bounded junk on half1
    const float t = tanh_(cc);
    const float tx = __shfl_xor(t, 16, 64);     // half1 <- tanh(c_real)
    const float hh = actB * tx;                 // half1: o * tanh(c)  (real)
    const float hb = __shfl_xor(hh, 16, 64);    // half0 <- real h
    return half ? hh : hb;
}

__global__ __launch_bounds__(64, 2) void lstm_dpp(
    const float* __restrict__ x,
    const float* __restrict__ w_in, const float* __restrict__ b_in,
    const float* __restrict__ w_ih0, const float* __restrict__ w_hh0,
    const float* __restrict__ b_ih0, const float* __restrict__ b_hh0,
    const float* __restrict__ w_ih1, const float* __restrict__ w_hh1,
    const float* __restrict__ b_ih1, const float* __restrict__ b_hh1,
    const float* __restrict__ fc_h_w, const float* __restrict__ fc_h_b,
    const float* __restrict__ fc_o_w, const float* __restrict__ fc_o_b,
    float* __restrict__ out, int B, int T)
{
    // only handles the b_in == 0 case; guard kernel covers the rest
    bool bzero = true;
    #pragma unroll
    for (int k = 0; k < 16; ++k)
        if (b_in[k] != 0.0f) bzero = false;
    if (!bzero) return;

    const int lane = threadIdx.x;       // 0..63
    const int e    = lane >> 5;         // element in block (0..1)
    const int sub  = lane & 31;
    const int j    = sub & 15;          // hidden unit / ring position
    const int half = sub >> 4;          // 0: rows {i,f}; 1: rows {g,o}
    const int elem  = blockIdx.x * EPW + e;
    const int elemc = elem < B ? elem : B - 1;
    const int rA = half * 32 + j;       // gate row A (i or g)
    const int rB = rA + 16;             // gate row B (f or o)

    __shared__ float hfin[EPW][16];
    __shared__ float zbuf[EPW][8];

    // ---- pre-rotated per-lane weights: W[s] = w[row][(j-s)&15]  (matches ror) ----
    float w0A[16], w0B[16], wi1A[16], wi1B[16], wh1A[16], wh1B[16];
    #pragma unroll
    for (int s = 0; s < 16; ++s) {
        const int k = (j - s) & 15;     // row_ror:S: lane j reads h[(j-S)&15]
        w0A[s]  = w_hh0[rA * 16 + k];
        w0B[s]  = w_hh0[rB * 16 + k];
        wi1A[s] = w_ih1[rA * 16 + k];
        wi1B[s] = w_ih1[rB * 16 + k];
        wh1A[s] = w_hh1[rA * 16 + k];
        wh1B[s] = w_hh1[rB * 16 + k];
    }
    float b00 = b_ih0[rA] + b_hh0[rA];
    float b01 = b_ih0[rB] + b_hh0[rB];
    float b10 = b_ih1[rA] + b_hh1[rA];
    float b11 = b_ih1[rB] + b_hh1[rB];

    // Fold linear_in(+ReLU) through w_ih0 (b_in == 0):
    //   x>0: term = x*Ap ; x<=0: x*An
    float ap0 = 0.0f, an0 = 0.0f, ap1 = 0.0f, an1 = 0.0f;
    #pragma unroll
    for (int k = 0; k < 16; ++k) {
        const float wk = w_in[k];
        const float wp = fmaxf(wk, 0.0f), wn = fminf(wk, 0.0f);
        const float wgA = w_ih0[rA * 16 + k];
        const float wgB = w_ih0[rB * 16 + k];
        ap0 = fmaf(wgA, wp, ap0); an0 = fmaf(wgA, wn, an0);
        ap1 = fmaf(wgB, wp, ap1); an1 = fmaf(wgB, wn, an1);
    }

    // ---- anti-remat pins: values become outputs of an opaque asm op, so the
    // allocator can neither rematerialize the loads inside the loop (R7's
    // VGPR=64 + ~300 reload ops/step) nor CSE them. Forces residency. ----
    #pragma unroll
    for (int s = 0; s < 16; ++s) {
        asm volatile("" : "+v"(w0A[s]), "+v"(w0B[s]), "+v"(wi1A[s]),
                          "+v"(wi1B[s]), "+v"(wh1A[s]), "+v"(wh1B[s]));
    }
    asm volatile("" : "+v"(b00), "+v"(b01), "+v"(b10), "+v"(b11));
    asm volatile("" : "+v"(ap0), "+v"(an0), "+v"(ap1), "+v"(an1));

    const float k2 = half ? 2.0f : 1.0f;

    float h0 = 0.0f, h1 = 0.0f, c0 = 0.0f, c1 = 0.0f;
    const float* xrow = x + (size_t)elemc * T;

    float xv = xrow[0];
    for (int t = 0; t < T; ++t) {
        const int tn = (t + 1 < T) ? (t + 1) : (T - 1);
        const float xn = xrow[tn];                     // prefetch next step

        // layer 0: a = x-term + b + w_hh0 . h0_{t-1}
        const bool xp = xv > 0.0f;
        float aA = fmaf(xv, xp ? ap0 : an0, b00);
        float aB = fmaf(xv, xp ? ap1 : an1, b01);
        DOTROT(aA, aB, h0, w0A, w0B);
        h0 = finishg(aA, aB, k2, half, c0);            // h0_t on all lanes

        // layer 1: b + w_ih1 . h0_t + w_hh1 . h1_{t-1}
        float bA = b10, bB = b11;
        DOTROT(bA, bB, h0, wi1A, wi1B);
        DOTROT(bA, bB, h1, wh1A, wh1B);
        h1 = finishg(bA, bB, k2, half, c1);            // h1_t on all lanes

        xv = xn;
    }

    // ---- head: fc_h (16->8) + ReLU, fc_o (8->1) ----
    if (half == 0) hfin[e][j] = h1;
    __syncthreads();
    if (half == 0 && j < 8) {
        float acc = fc_h_b[j];
        #pragma unroll
        for (int k = 0; k < 16; ++k)
            acc = fmaf(fc_h_w[j * 16 + k], hfin[e][k], acc);
        zbuf[e][j] = fmaxf(acc, 0.0f);
    }
    __syncthreads();
    if (sub == 0 && elem < B) {
        float acc = fc_o_b[0];
        #pragma unroll
        for (int r = 0; r < 8; ++r) acc = fmaf(fc_o_w[r], zbuf[e][r], acc);
        out[elem] = acc;
    }
}

// ---------------- guard kernel: general b_in != 0 path (R5 code, self-gating) ----------------

__device__ __forceinline__ float lstm_finish_g(v2f aA, v2f aB, float kA, float c1A,
                                               float c2A, float& cc) {
    const float hA = aA[0] + aA[1];
    const float hB = aB[0] + aB[1];
    const float actA =
        fmaf(c2A, __builtin_amdgcn_rcpf(1.0f + __builtin_amdgcn_exp2f(kA * hA)), c1A);
    const float actB = sigm(hB);
    const float xg = __shfl_xor(actA, 16, 64);
    cc = fmaf(actB, cc, actA * xg);
    const float t = tanh_(cc);
    const float tx = __shfl_xor(t, 16, 64);
    return actB * tx;
}

#define DOTRG(AA, AB, W, HP)                                          \
    _Pragma("unroll")                                                 \
    for (int c = 0; c < 4; ++c) {                                     \
        v2f hlo = {HP[c].x, HP[c].y};                                 \
        v2f hhi = {HP[c].z, HP[c].w};                                 \
        AA = __builtin_elementwise_fma(W[0][2 * c], hlo, AA);         \
        AA = __builtin_elementwise_fma(W[0][2 * c + 1], hhi, AA);     \
        AB = __builtin_elementwise_fma(W[1][2 * c], hlo, AB);         \
        AB = __builtin_elementwise_fma(W[1][2 * c + 1], hhi, AB);     \
    }

#define DOTLG(AA, AB, WROWA, WROWB, HP)                               \
    _Pragma("unroll")                                                 \
    for (int c = 0; c < 4; ++c) {                                     \
        float4 wa = ((const float4*)(WROWA))[c];                      \
        float4 wb = ((const float4*)(WROWB))[c];                      \
        v2f hlo = {HP[c].x, HP[c].y};                                 \
        v2f hhi = {HP[c].z, HP[c].w};                                 \
        AA = __builtin_elementwise_fma((v2f){wa.x, wa.y}, hlo, AA);   \
        AA = __builtin_elementwise_fma((v2f){wa.z, wa.w}, hhi, AA);   \
        AB = __builtin_elementwise_fma((v2f){wb.x, wb.y}, hlo, AB);   \
        AB = __builtin_elementwise_fma((v2f){wb.z, wb.w}, hhi, AB);   \
    }

__global__ __launch_bounds__(64, 2) void lstm_general(
    const float* __restrict__ x,
    const float* __restrict__ w_in, const float* __restrict__ b_in,
    const float* __restrict__ w_ih0, const float* __restrict__ w_hh0,
    const float* __restrict__ b_ih0, const float* __restrict__ b_hh0,
    const float* __restrict__ w_ih1, const float* __restrict__ w_hh1,
    const float* __restrict__ b_ih1, const float* __restrict__ b_hh1,
    const float* __restrict__ fc_h_w, const float* __restrict__ fc_h_b,
    const float* __restrict__ fc_o_w, const float* __restrict__ fc_o_b,
    float* __restrict__ out, int B, int T)
{
    bool bzero = true;
    #pragma unroll
    for (int k = 0; k < 16; ++k)
        if (b_in[k] != 0.0f) bzero = false;
    if (bzero) return;                  // fast kernel handles this case

    const int lane = threadIdx.x;
    const int e    = lane >> 5;
    const int sub  = lane & 31;
    const int j    = sub & 15;
    const int half = sub >> 4;
    const int elem  = blockIdx.x * EPW + e;
    const int elemc = elem < B ? elem : B - 1;
    const int rA = half * 32 + j;
    const int rB = rA + 16;

    __shared__ float  whh0s[64][20];
    __shared__ float4 h0b[2][EPW][4];
    __shared__ float4 h1b[2][EPW][4];
    __shared__ float  xib[EPW][16];

    {
        const int r = lane;
        const float4* src = (const float4*)(w_hh0 + r * 16);
        float4* dst = (float4*)&whh0s[r][0];
        #pragma unroll
        for (int c = 0; c < 4; ++c) dst[c] = src[c];
    }

    v2f wi1[2][8], wh1[2][8];
    float bb0[2], bb1[2];
    #pragma unroll
    for (int g = 0; g < 2; ++g) {
        const int row = g ? rB : rA;
        const float4* pi = (const float4*)(w_ih1 + row * 16);
        const float4* ph = (const float4*)(w_hh1 + row * 16);
        #pragma unroll
        for (int c = 0; c < 4; ++c) {
            float4 ti = pi[c], th = ph[c];
            wi1[g][2 * c]     = (v2f){ti.x, ti.y};
            wi1[g][2 * c + 1] = (v2f){ti.z, ti.w};
            wh1[g][2 * c]     = (v2f){th.x, th.y};
            wh1[g][2 * c + 1] = (v2f){th.z, th.w};
        }
        bb0[g] = b_ih0[row] + b_hh0[row];
        bb1[g] = b_ih1[row] + b_hh1[row];
    }

    const float kA  = half ? (2.0f * L2E) : (-L2E);
    const float c1A = half ? 1.0f : 0.0f;
    const float c2A = half ? -2.0f : 1.0f;

    if (half) {
        ((float*)&h0b[0][e][0])[j] = 0.0f;
        ((float*)&h1b[0][e][0])[j] = 0.0f;
    }
    float c0 = 0.0f, c1 = 0.0f;
    int p = 0;

    const float* xrow = x + (size_t)elemc * T;
    const float* wlA = &whh0s[rA][0];
    const float* wlB = &whh0s[rB][0];
    const float4* giA = (const float4*)(w_ih0 + rA * 16);
    const float4* giB = (const float4*)(w_ih0 + rB * 16);

    for (int t = 0; t < T; ++t) {
        const float xv = xrow[t];
        if (half == 0) xib[e][j] = fmaxf(fmaf(xv, w_in[j], b_in[j]), 0.0f);
        __syncthreads();
        float4 xi4[4];
        #pragma unroll
        for (int c = 0; c < 4; ++c) xi4[c] = *(const float4*)&xib[e][4 * c];
        v2f aA = {bb0[0], 0.0f};
        v2f aB = {bb0[1], 0.0f};
        DOTLG(aA, aB, giA, giB, xi4);
        float4 hp[4];
        #pragma unroll
        for (int c = 0; c < 4; ++c) hp[c] = h0b[p][e][c];
        DOTLG(aA, aB, wlA, wlB, hp);
        const float h0j = lstm_finish_g(aA, aB, kA, c1A, c2A, c0);
        if (half) ((float*)&h0b[p ^ 1][e][0])[j] = h0j;

        float4 hq[4];
        #pragma unroll
        for (int c = 0; c < 4; ++c) hq[c] = h1b[p][e][c];
        v2f bA = {bb1[0], 0.0f};
        v2f bB = {bb1[1], 0.0f};
        DOTRG(bA, bB, wh1, hq);
        __syncthreads();
        float4 hn[4];
        #pragma unroll
        for (int c = 0; c < 4; ++c) hn[c] = h0b[p ^ 1][e][c];
        DOTRG(bA, bB, wi1, hn);
        const float h1j = lstm_finish_g(bA, bB, kA, c1A, c2A, c1);
        if (half) ((float*)&h1b[p ^ 1][e][0])[j] = h1j;
        __syncthreads();
        p ^= 1;
    }

    if (half == 0 && j < 8) {
        float acc = fc_h_b[j];
        #pragma unroll
        for (int c = 0; c < 4; ++c) {
            float4 hv = h1b[p][e][c];
            acc = fmaf(fc_h_w[j * 16 + 4 * c + 0], hv.x, acc);
            acc = fmaf(fc_h_w[j * 16 + 4 * c + 1], hv.y, acc);
            acc = fmaf(fc_h_w[j * 16 + 4 * c + 2], hv.z, acc);
            acc = fmaf(fc_h_w[j * 16 + 4 * c + 3], hv.w, acc);
        }
        xib[e][j] = fmaxf(acc, 0.0f);
    }
    __syncthreads();
    if (sub == 0 && elem < B) {
        float acc = fc_o_b[0];
        #pragma unroll
        for (int r = 0; r < 8; ++r) acc = fmaf(fc_o_w[r], xib[e][r], acc);
        out[elem] = acc;
    }
}

extern "C" void kernel_launch(void* const* d_in, const int* in_sizes, int n_in,
                              void* d_out, int out_size, void* d_ws, size_t ws_size,
                              hipStream_t stream) {
    const float* x      = (const float*)d_in[0];
    const float* w_in   = (const float*)d_in[1];
    const float* b_in   = (const float*)d_in[2];
    const float* w_ih0  = (const float*)d_in[3];
    const float* w_hh0  = (const float*)d_in[4];
    const float* b_ih0  = (const float*)d_in[5];
    const float* b_hh0  = (const float*)d_in[6];
    const float* w_ih1  = (const float*)d_in[7];
    const float* w_hh1  = (const float*)d_in[8];
    const float* b_ih1  = (const float*)d_in[9];
    const float* b_hh1  = (const float*)d_in[10];
    const float* fc_h_w = (const float*)d_in[11];
    const float* fc_h_b = (const float*)d_in[12];
    const float* fc_o_w = (const float*)d_in[13];
    const float* fc_o_b = (const float*)d_in[14];

    const int B = out_size;                 // x is [B,T,1]
    const int T = in_sizes[0] / (B > 0 ? B : 1);
    const int grid = (B + EPW - 1) / EPW;

    hipLaunchKernelGGL(lstm_dpp, dim3(grid), dim3(64), 0, stream,
                       x, w_in, b_in, w_ih0, w_hh0, b_ih0, b_hh0,
                       w_ih1, w_hh1, b_ih1, b_hh1, fc_h_w, fc_h_b,
                       fc_o_w, fc_o_b, (float*)d_out, B, T);
    hipLaunchKernelGGL(lstm_general, dim3(grid), dim3(64), 0, stream,
                       x, w_in, b_in, w_ih0, w_hh0, b_ih0, b_hh0,
                       w_ih1, w_hh1, b_ih1, b_hh1, fc_h_w, fc_h_b,
                       fc_o_w, fc_o_b, (float*)d_out, B, T);
}

// Round 9
// 221.810 us; speedup vs baseline: 1.8940x; 1.8940x over previous
//
#include <hip/hip_runtime.h>
#include <math.h>

// LSTMLightweight on MI355X (R9: R2's EPW=4 all-gates layout, spill-free).
//   x[B,T,1] -> linear_in(1->16)+ReLU -> LSTM0(16) -> LSTM1(16) -> fc(16->8)+ReLU -> fc(8->1)
// Ladder: R2 (EPW4, spilled) 233us | R5 (EPW2, LDS) 353 | R7/8 (EPW2, DPP) 420.
// EPW=4 wins structurally: 16 lanes/element, lane j owns ALL 4 gate rows of
// unit j -> no cross-lane shuffles in the gate math at all; 2048 blocks.
// Dots are terms-packed v2f pk_fma (even/odd terms in lo/hi; horizontal add in
// finish) — R2-proven. h exchanged via double-buffered LDS rows with
// broadcast-pattern float4 reads (16 lanes same addr -> conflict-free) and two
// __syncthreads()/step (R4/R5-proven ordering).
// Allocator: weights 192 f32 + working ~= 230 VGPR. Grid gives only 2
// waves/SIMD, so amdgpu_waves_per_eu(1,2) tells the backend max-2-waves is
// fine -> 256-reg budget, no reason to spill (R2's disease) or AGPR-park
// (R7/R8's disease, VGPR=64 + copy traffic).
// b_in!=0 handled by the separate self-gating guard kernel (R5 code, proven).

#define EPW 4
#define L2E 1.4426950408889634f

typedef float v2f __attribute__((ext_vector_type(2)));

__device__ __forceinline__ float sigm(float v) {
    return __builtin_amdgcn_rcpf(1.0f + __builtin_amdgcn_exp2f(-L2E * v));
}
__device__ __forceinline__ float tanh_(float v) {
    // tanh(v) = 1 - 2/(exp(2v)+1); saturates correctly at +-inf
    return 1.0f - 2.0f * __builtin_amdgcn_rcpf(1.0f + __builtin_amdgcn_exp2f((2.0f * L2E) * v));
}

// terms-packed dot: ACC[g] (v2f: even/odd partial sums) += W[g][.] . h-row
#define DOTP4(ACC, W, HROW)                                           \
    _Pragma("unroll")                                                 \
    for (int c = 0; c < 4; ++c) {                                     \
        const float4 h4_ = *(const float4*)((HROW) + 4 * c);          \
        const v2f lo_ = {h4_.x, h4_.y};                               \
        const v2f hi_ = {h4_.z, h4_.w};                               \
        _Pragma("unroll")                                             \
        for (int g = 0; g < 4; ++g) {                                 \
            ACC[g] = __builtin_elementwise_fma(W[g][2 * c], lo_, ACC[g]);     \
            ACC[g] = __builtin_elementwise_fma(W[g][2 * c + 1], hi_, ACC[g]); \
        }                                                             \
    }

__global__ __launch_bounds__(64) __attribute__((amdgpu_waves_per_eu(1, 2)))
void lstm_pk(
    const float* __restrict__ x,
    const float* __restrict__ w_in, const float* __restrict__ b_in,
    const float* __restrict__ w_ih0, const float* __restrict__ w_hh0,
    const float* __restrict__ b_ih0, const float* __restrict__ b_hh0,
    const float* __restrict__ w_ih1, const float* __restrict__ w_hh1,
    const float* __restrict__ b_ih1, const float* __restrict__ b_hh1,
    const float* __restrict__ fc_h_w, const float* __restrict__ fc_h_b,
    const float* __restrict__ fc_o_w, const float* __restrict__ fc_o_b,
    float* __restrict__ out, int B, int T)
{
    // only handles the b_in == 0 case; guard kernel covers the rest
    bool bzero = true;
    #pragma unroll
    for (int k = 0; k < 16; ++k)
        if (b_in[k] != 0.0f) bzero = false;
    if (!bzero) return;

    const int lane = threadIdx.x;       // 0..63
    const int e    = lane >> 4;         // element in block (0..3)
    const int j    = lane & 15;         // hidden unit; lane owns gate rows g*16+j
    const int elem  = blockIdx.x * EPW + e;
    const int elemc = elem < B ? elem : B - 1;

    __shared__ float h0b[2][EPW][16];   // double-buffered h exchange
    __shared__ float h1b[2][EPW][16];
    __shared__ float zb[EPW][8];

    // ---- weights: rows {i,f,g,o} of unit j, packed as v2f term-pairs ----
    v2f wh0[4][8], wi1[4][8], wh1[4][8];
    float b0[4], b1[4], ap[4], an[4];
    #pragma unroll
    for (int g = 0; g < 4; ++g) {
        const int r = g * 16 + j;
        const v2f* p0 = (const v2f*)(w_hh0 + r * 16);
        const v2f* p1 = (const v2f*)(w_ih1 + r * 16);
        const v2f* p2 = (const v2f*)(w_hh1 + r * 16);
        #pragma unroll
        for (int q = 0; q < 8; ++q) {
            wh0[g][q] = p0[q];
            wi1[g][q] = p1[q];
            wh1[g][q] = p2[q];
        }
        b0[g] = b_ih0[r] + b_hh0[r];
        b1[g] = b_ih1[r] + b_hh1[r];
        ap[g] = 0.0f; an[g] = 0.0f;
    }
    // Fold linear_in(+ReLU) through w_ih0 (b_in == 0):
    //   x>0: term = x*Ap ; x<=0: x*An
    #pragma unroll
    for (int k = 0; k < 16; ++k) {
        const float wk = w_in[k];
        const float wp = fmaxf(wk, 0.0f), wn = fminf(wk, 0.0f);
        #pragma unroll
        for (int g = 0; g < 4; ++g) {
            const float wg = w_ih0[(g * 16 + j) * 16 + k];
            ap[g] = fmaf(wg, wp, ap[g]);
            an[g] = fmaf(wg, wn, an[g]);
        }
    }

    // ---- zero state (read-buffer 0) ----
    h0b[0][e][j] = 0.0f;
    h1b[0][e][j] = 0.0f;
    float c0 = 0.0f, c1 = 0.0f;
    int p = 0;                          // read-buffer parity
    __syncthreads();

    const float* xrow = x + (size_t)elemc * T;
    float xv = xrow[0];

    for (int t = 0; t < T; ++t) {
        const int tn = (t + 1 < T) ? (t + 1) : (T - 1);
        const float xn = xrow[tn];                       // prefetch next step

        // ---- layer 0: a = x-term + b0 + w_hh0 . h0_{t-1} ----
        const bool xp = xv > 0.0f;
        v2f a[4];
        #pragma unroll
        for (int g = 0; g < 4; ++g)
            a[g] = (v2f){fmaf(xv, xp ? ap[g] : an[g], b0[g]), 0.0f};
        DOTP4(a, wh0, &h0b[p][e][0]);
        {
            const float aI = a[0][0] + a[0][1];
            const float aF = a[1][0] + a[1][1];
            const float aG = a[2][0] + a[2][1];
            const float aO = a[3][0] + a[3][1];
            const float ig = sigm(aI), fg = sigm(aF);
            const float gv = tanh_(aG), og = sigm(aO);
            c0 = fmaf(fg, c0, ig * gv);
            h0b[p ^ 1][e][j] = og * tanh_(c0);           // h0_t
        }
        __syncthreads();                                 // h0_t visible

        // ---- layer 1: b1 + w_ih1 . h0_t + w_hh1 . h1_{t-1} ----
        v2f b[4];
        #pragma unroll
        for (int g = 0; g < 4; ++g) b[g] = (v2f){b1[g], 0.0f};
        DOTP4(b, wi1, &h0b[p ^ 1][e][0]);
        DOTP4(b, wh1, &h1b[p][e][0]);
        {
            const float aI = b[0][0] + b[0][1];
            const float aF = b[1][0] + b[1][1];
            const float aG = b[2][0] + b[2][1];
            const float aO = b[3][0] + b[3][1];
            const float ig = sigm(aI), fg = sigm(aF);
            const float gv = tanh_(aG), og = sigm(aO);
            c1 = fmaf(fg, c1, ig * gv);
            h1b[p ^ 1][e][j] = og * tanh_(c1);           // h1_t
        }
        __syncthreads();                                 // h1_t visible
        p ^= 1;
        xv = xn;
    }

    // ---- head: fc_h (16->8) + ReLU, fc_o (8->1) ----
    if (j < 8) {
        float acc = fc_h_b[j];
        const float* h1p = &h1b[p][e][0];
        #pragma unroll
        for (int k = 0; k < 16; ++k)
            acc = fmaf(fc_h_w[j * 16 + k], h1p[k], acc);
        zb[e][j] = fmaxf(acc, 0.0f);
    }
    __syncthreads();
    if (j == 0 && elem < B) {
        float acc = fc_o_b[0];
        #pragma unroll
        for (int r = 0; r < 8; ++r) acc = fmaf(fc_o_w[r], zb[e][r], acc);
        out[elem] = acc;
    }
}

// ---------------- guard kernel: general b_in != 0 path (R5 code, self-gating) ----------------

typedef float v2fg __attribute__((ext_vector_type(2)));

__device__ __forceinline__ float lstm_finish_g(v2fg aA, v2fg aB, float kA, float c1A,
                                               float c2A, float& cc) {
    const float hA = aA[0] + aA[1];
    const float hB = aB[0] + aB[1];
    const float actA =
        fmaf(c2A, __builtin_amdgcn_rcpf(1.0f + __builtin_amdgcn_exp2f(kA * hA)), c1A);
    const float actB = sigm(hB);
    const float xg = __shfl_xor(actA, 16, 64);
    cc = fmaf(actB, cc, actA * xg);
    const float t = tanh_(cc);
    const float tx = __shfl_xor(t, 16, 64);
    return actB * tx;
}

#define DOTRG(AA, AB, W, HP)                                          \
    _Pragma("unroll")                                                 \
    for (int c = 0; c < 4; ++c) {                                     \
        v2fg hlo = {HP[c].x, HP[c].y};                                \
        v2fg hhi = {HP[c].z, HP[c].w};                                \
        AA = __builtin_elementwise_fma(W[0][2 * c], hlo, AA);         \
        AA = __builtin_elementwise_fma(W[0][2 * c + 1], hhi, AA);     \
        AB = __builtin_elementwise_fma(W[1][2 * c], hlo, AB);         \
        AB = __builtin_elementwise_fma(W[1][2 * c + 1], hhi, AB);     \
    }

#define DOTLG(AA, AB, WROWA, WROWB, HP)                               \
    _Pragma("unroll")                                                 \
    for (int c = 0; c < 4; ++c) {                                     \
        float4 wa = ((const float4*)(WROWA))[c];                      \
        float4 wb = ((const float4*)(WROWB))[c];                      \
        v2fg hlo = {HP[c].x, HP[c].y};                                \
        v2fg hhi = {HP[c].z, HP[c].w};                                \
        AA = __builtin_elementwise_fma((v2fg){wa.x, wa.y}, hlo, AA);  \
        AA = __builtin_elementwise_fma((v2fg){wa.z, wa.w}, hhi, AA);  \
        AB = __builtin_elementwise_fma((v2fg){wb.x, wb.y}, hlo, AB);  \
        AB = __builtin_elementwise_fma((v2fg){wb.z, wb.w}, hhi, AB);  \
    }

__global__ __launch_bounds__(64, 2) void lstm_general(
    const float* __restrict__ x,
    const float* __restrict__ w_in, const float* __restrict__ b_in,
    const float* __restrict__ w_ih0, const float* __restrict__ w_hh0,
    const float* __restrict__ b_ih0, const float* __restrict__ b_hh0,
    const float* __restrict__ w_ih1, const float* __restrict__ w_hh1,
    const float* __restrict__ b_ih1, const float* __restrict__ b_hh1,
    const float* __restrict__ fc_h_w, const float* __restrict__ fc_h_b,
    const float* __restrict__ fc_o_w, const float* __restrict__ fc_o_b,
    float* __restrict__ out, int B, int T)
{
    bool bzero = true;
    #pragma unroll
    for (int k = 0; k < 16; ++k)
        if (b_in[k] != 0.0f) bzero = false;
    if (bzero) return;                  // fast kernel handles this case

    const int lane = threadIdx.x;
    const int e    = lane >> 5;
    const int sub  = lane & 31;
    const int j    = sub & 15;
    const int half = sub >> 4;
    const int elem  = blockIdx.x * 2 + e;
    const int elemc = elem < B ? elem : B - 1;
    const int rA = half * 32 + j;
    const int rB = rA + 16;

    __shared__ float  whh0s[64][20];
    __shared__ float4 h0g[2][2][4];
    __shared__ float4 h1g[2][2][4];
    __shared__ float  xib[2][16];

    {
        const int r = lane;
        const float4* src = (const float4*)(w_hh0 + r * 16);
        float4* dst = (float4*)&whh0s[r][0];
        #pragma unroll
        for (int c = 0; c < 4; ++c) dst[c] = src[c];
    }

    v2fg wi1[2][8], wh1[2][8];
    float bb0[2], bb1[2];
    #pragma unroll
    for (int g = 0; g < 2; ++g) {
        const int row = g ? rB : rA;
        const float4* pi = (const float4*)(w_ih1 + row * 16);
        const float4* ph = (const float4*)(w_hh1 + row * 16);
        #pragma unroll
        for (int c = 0; c < 4; ++c) {
            float4 ti = pi[c], th = ph[c];
            wi1[g][2 * c]     = (v2fg){ti.x, ti.y};
            wi1[g][2 * c + 1] = (v2fg){ti.z, ti.w};
            wh1[g][2 * c]     = (v2fg){th.x, th.y};
            wh1[g][2 * c + 1] = (v2fg){th.z, th.w};
        }
        bb0[g] = b_ih0[row] + b_hh0[row];
        bb1[g] = b_ih1[row] + b_hh1[row];
    }

    const float kA  = half ? (2.0f * L2E) : (-L2E);
    const float c1A = half ? 1.0f : 0.0f;
    const float c2A = half ? -2.0f : 1.0f;

    if (half) {
        ((float*)&h0g[0][e][0])[j] = 0.0f;
        ((float*)&h1g[0][e][0])[j] = 0.0f;
    }
    float c0 = 0.0f, c1 = 0.0f;
    int p = 0;

    const float* xrow = x + (size_t)elemc * T;
    const float* wlA = &whh0s[rA][0];
    const float* wlB = &whh0s[rB][0];
    const float4* giA = (const float4*)(w_ih0 + rA * 16);
    const float4* giB = (const float4*)(w_ih0 + rB * 16);

    for (int t = 0; t < T; ++t) {
        const float xv = xrow[t];
        if (half == 0) xib[e][j] = fmaxf(fmaf(xv, w_in[j], b_in[j]), 0.0f);
        __syncthreads();
        float4 xi4[4];
        #pragma unroll
        for (int c = 0; c < 4; ++c) xi4[c] = *(const float4*)&xib[e][4 * c];
        v2fg aA = {bb0[0], 0.0f};
        v2fg aB = {bb0[1], 0.0f};
        DOTLG(aA, aB, giA, giB, xi4);
        float4 hp[4];
        #pragma unroll
        for (int c = 0; c < 4; ++c) hp[c] = h0g[p][e][c];
        DOTLG(aA, aB, wlA, wlB, hp);
        const float h0j = lstm_finish_g(aA, aB, kA, c1A, c2A, c0);
        if (half) ((float*)&h0g[p ^ 1][e][0])[j] = h0j;

        float4 hq[4];
        #pragma unroll
        for (int c = 0; c < 4; ++c) hq[c] = h1g[p][e][c];
        v2fg bA = {bb1[0], 0.0f};
        v2fg bB = {bb1[1], 0.0f};
        DOTRG(bA, bB, wh1, hq);
        __syncthreads();
        float4 hn[4];
        #pragma unroll
        for (int c = 0; c < 4; ++c) hn[c] = h0g[p ^ 1][e][c];
        DOTRG(bA, bB, wi1, hn);
        const float h1j = lstm_finish_g(bA, bB, kA, c1A, c2A, c1);
        if (half) ((float*)&h1g[p ^ 1][e][0])[j] = h1j;
        __syncthreads();
        p ^= 1;
    }

    if (half == 0 && j < 8) {
        float acc = fc_h_b[j];
        #pragma unroll
        for (int c = 0; c < 4; ++c) {
            float4 hv = h1g[p][e][c];
            acc = fmaf(fc_h_w[j * 16 + 4 * c + 0], hv.x, acc);
            acc = fmaf(fc_h_w[j * 16 + 4 * c + 1], hv.y, acc);
            acc = fmaf(fc_h_w[j * 16 + 4 * c + 2], hv.z, acc);
            acc = fmaf(fc_h_w[j * 16 + 4 * c + 3], hv.w, acc);
        }
        xib[e][j] = fmaxf(acc, 0.0f);
    }
    __syncthreads();
    if (sub == 0 && elem < B) {
        float acc = fc_o_b[0];
        #pragma unroll
        for (int r = 0; r < 8; ++r) acc = fmaf(fc_o_w[r], xib[e][r], acc);
        out[elem] = acc;
    }
}

extern "C" void kernel_launch(void* const* d_in, const int* in_sizes, int n_in,
                              void* d_out, int out_size, void* d_ws, size_t ws_size,
                              hipStream_t stream) {
    const float* x      = (const float*)d_in[0];
    const float* w_in   = (const float*)d_in[1];
    const float* b_in   = (const float*)d_in[2];
    const float* w_ih0  = (const float*)d_in[3];
    const float* w_hh0  = (const float*)d_in[4];
    const float* b_ih0  = (const float*)d_in[5];
    const float* b_hh0  = (const float*)d_in[6];
    const float* w_ih1  = (const float*)d_in[7];
    const float* w_hh1  = (const float*)d_in[8];
    const float* b_ih1  = (const float*)d_in[9];
    const float* b_hh1  = (const float*)d_in[10];
    const float* fc_h_w = (const float*)d_in[11];
    const float* fc_h_b = (const float*)d_in[12];
    const float* fc_o_w = (const float*)d_in[13];
    const float* fc_o_b = (const float*)d_in[14];

    const int B = out_size;                 // x is [B,T,1]
    const int T = in_sizes[0] / (B > 0 ? B : 1);

    const int gridf = (B + EPW - 1) / EPW;
    hipLaunchKernelGGL(lstm_pk, dim3(gridf), dim3(64), 0, stream,
                       x, w_in, b_in, w_ih0, w_hh0, b_ih0, b_hh0,
                       w_ih1, w_hh1, b_ih1, b_hh1, fc_h_w, fc_h_b,
                       fc_o_w, fc_o_b, (float*)d_out, B, T);
    const int gridg = (B + 1) / 2;
    hipLaunchKernelGGL(lstm_general, dim3(gridg), dim3(64), 0, stream,
                       x, w_in, b_in, w_ih0, w_hh0, b_ih0, b_hh0,
                       w_ih1, w_hh1, b_ih1, b_hh1, fc_h_w, fc_h_b,
                       fc_o_w, fc_o_b, (float*)d_out, B, T);
}